// Round 2
// baseline (921.367 us; speedup 1.0000x reference)
//
#include <hip/hip_runtime.h>

#define N_TOK 16384
#define H_DIM 4096
#define H4    1024      // H/4 (float4 count per row)
#define P_DIM 6
#define E_NUM 64
#define K_TOP 8
#define BLOCK 1024      // 16 waves
#define WAVES 16
#define GRID  256       // 1 block per CU
#define TOK_PER_BLOCK 64   // N_TOK / GRID
#define TW 4               // tokens per wave
#define NIT (H4 / 64)      // 16 main-loop iterations

// native clang vector: __builtin_nontemporal_load requires this, not HIP float4
typedef float f4 __attribute__((ext_vector_type(4)));

// 96KB LDS -> 1 block/CU; 16 waves = 4 waves/SIMD -> hard 128-VGPR cap.
__launch_bounds__(BLOCK, 4)
__global__ void kdtree_router_kernel(const float* __restrict__ x,
                                     const float* __restrict__ pca_mean,
                                     const float* __restrict__ pca_comp,
                                     const float* __restrict__ centroids,
                                     float* __restrict__ out) {
    // LDS: W staged as [p][h4] f4 (96 KB) + centroids transposed + reduce scratch
    __shared__ f4    sW4[P_DIM * H4];
    __shared__ float sC[P_DIM * E_NUM];
    __shared__ float sRed[WAVES * P_DIM];

    const int tid  = threadIdx.x;
    const int wave = tid >> 6;
    const int lane = tid & 63;

    const f4* Wg4   = (const f4*)pca_comp;
    const f4* mean4 = (const f4*)pca_mean;
    const f4* x4    = (const f4*)x;

    const int n0 = blockIdx.x * TOK_PER_BLOCK + wave * TW;

    // ---- issue x prefetch for iterations 0 and 1 BEFORE staging W ----
    // x is the 268MB stream; get its HBM reads in flight while we stage the
    // 96KB of W + barrier. Nontemporal: streamed once, no reuse, > L3 size.
    f4 xc[TW], xn[TW];
    #pragma unroll
    for (int t = 0; t < TW; ++t)
        xc[t] = __builtin_nontemporal_load(x4 + (n0 + t) * H4 + lane);
    #pragma unroll
    for (int t = 0; t < TW; ++t)
        xn[t] = __builtin_nontemporal_load(x4 + (n0 + t) * H4 + 64 + lane);

    // stage centroids transposed: sC[p][e] = centroids[e*6+p]
    if (tid < E_NUM * P_DIM) {
        int e = tid / P_DIM, p = tid - e * P_DIM;
        sC[p * E_NUM + e] = centroids[tid];
    }

    // stage W into LDS (1024 threads -> exactly one f4 per thread per p);
    // simultaneously compute mean_proj[p] = mean . W[p]
    const f4 m4 = mean4[tid];
    #pragma unroll
    for (int p = 0; p < P_DIM; ++p) {
        f4 w = Wg4[p * H4 + tid];
        sW4[p * H4 + tid] = w;
        float sp = w.x * m4.x + w.y * m4.y + w.z * m4.z + w.w * m4.w;
        #pragma unroll
        for (int off = 32; off > 0; off >>= 1) sp += __shfl_xor(sp, off, 64);
        if (lane == 0) sRed[wave * P_DIM + p] = sp;
    }
    __syncthreads();

    float mp[P_DIM];
    #pragma unroll
    for (int p = 0; p < P_DIM; ++p) {
        float s = 0.f;
        #pragma unroll
        for (int w = 0; w < WAVES; ++w) s += sRed[w * P_DIM + p];
        mp[p] = s;
    }

    float* out_idx = out;                       // [N,8] indices (as float)
    float* out_tp  = out + N_TOK * K_TOP;       // [N,8] renormalized top-k probs
    float* out_pr  = out + 2 * N_TOK * K_TOP;   // [N,64] full softmax

    float acc[TW][P_DIM];
    #pragma unroll
    for (int t = 0; t < TW; ++t)
        #pragma unroll
        for (int p = 0; p < P_DIM; ++p) acc[t][p] = 0.f;

    // main loop: compute iteration `it` on xc, with xn (it+1) resident/in-flight
    // and xf (it+2) issued before the FMAs -> ~2 iterations of latency cover.
    for (int it = 0; it < NIT; ++it) {
        const int h4 = it * 64 + lane;
        f4 w[P_DIM];
        #pragma unroll
        for (int p = 0; p < P_DIM; ++p) w[p] = sW4[p * H4 + h4];

        f4 xf[TW];
        const bool more = (it + 2 < NIT);
        if (more) {
            const int h4f = (it + 2) * 64 + lane;
            #pragma unroll
            for (int t = 0; t < TW; ++t)
                xf[t] = __builtin_nontemporal_load(x4 + (n0 + t) * H4 + h4f);
        }

        #pragma unroll
        for (int t = 0; t < TW; ++t) {
            #pragma unroll
            for (int p = 0; p < P_DIM; ++p) {
                acc[t][p] += xc[t].x * w[p].x + xc[t].y * w[p].y
                           + xc[t].z * w[p].z + xc[t].w * w[p].w;
            }
        }

        #pragma unroll
        for (int t = 0; t < TW; ++t) xc[t] = xn[t];
        if (more) {
            #pragma unroll
            for (int t = 0; t < TW; ++t) xn[t] = xf[t];
        }
    }

    // per-token epilogue: reduce proj, distances, softmax, top-8
    #pragma unroll
    for (int t = 0; t < TW; ++t) {
        const int n = n0 + t;
        float pr[P_DIM];
        #pragma unroll
        for (int p = 0; p < P_DIM; ++p) {
            float v = acc[t][p];
            #pragma unroll
            for (int off = 32; off > 0; off >>= 1) v += __shfl_xor(v, off, 64);
            pr[p] = v - mp[p];
        }

        // lane e computes distance to centroid e (direct form, >= 0)
        float d2 = 0.f;
        #pragma unroll
        for (int p = 0; p < P_DIM; ++p) {
            float diff = pr[p] - sC[p * E_NUM + lane];
            d2 += diff * diff;
        }
        float dist = sqrtf(d2);

        // softmax(-dist) across 64 lanes
        float mn = dist;
        #pragma unroll
        for (int off = 32; off > 0; off >>= 1) mn = fminf(mn, __shfl_xor(mn, off, 64));
        float ev  = __expf(mn - dist);
        float sum = ev;
        #pragma unroll
        for (int off = 32; off > 0; off >>= 1) sum += __shfl_xor(sum, off, 64);
        float prob = ev / sum;
        out_pr[n * E_NUM + lane] = prob;

        // top-8 via repeated butterfly argmax (ties -> lower index, matches lax.top_k)
        float v = prob; int idx = lane;
        float tsum = 0.f, myv = 0.f; int myi = 0;
        #pragma unroll
        for (int r = 0; r < K_TOP; ++r) {
            float bv = v; int bi = idx;
            #pragma unroll
            for (int off = 32; off > 0; off >>= 1) {
                float ov = __shfl_xor(bv, off, 64);
                int   oi = __shfl_xor(bi, off, 64);
                if (ov > bv || (ov == bv && oi < bi)) { bv = ov; bi = oi; }
            }
            tsum += bv;
            if (lane == r) { myv = bv; myi = bi; }
            if (idx == bi) v = -1.f;   // remove winner (probs are > 0)
        }
        if (lane < K_TOP) {
            out_idx[n * K_TOP + lane] = (float)myi;
            out_tp [n * K_TOP + lane] = myv / tsum;
        }
    }
}

extern "C" void kernel_launch(void* const* d_in, const int* in_sizes, int n_in,
                              void* d_out, int out_size, void* d_ws, size_t ws_size,
                              hipStream_t stream) {
    const float* x         = (const float*)d_in[0];
    const float* pca_mean  = (const float*)d_in[1];
    const float* pca_comp  = (const float*)d_in[2];
    const float* centroids = (const float*)d_in[3];
    // d_in[4] = top_k (known constant 8)
    float* out = (float*)d_out;

    kdtree_router_kernel<<<GRID, BLOCK, 0, stream>>>(x, pca_mean, pca_comp, centroids, out);
}

// Round 3
// 917.759 us; speedup vs baseline: 1.0039x; 1.0039x over previous
//
#include <hip/hip_runtime.h>

#define N_TOK 16384
#define H_DIM 4096
#define H4    1024      // H/4 (float4 count per row)
#define P_DIM 6
#define E_NUM 64
#define K_TOP 8
#define BLOCK 1024      // 16 waves
#define WAVES 16
#define GRID  256       // 1 block per CU
#define TOK_PER_BLOCK 64   // N_TOK / GRID
#define TW 4               // tokens per wave
#define NIT (H4 / 64)      // 16 main-loop iterations

// native clang vector: __builtin_nontemporal_load requires this, not HIP float4
typedef float f4 __attribute__((ext_vector_type(4)));

// NOTE: no second launch_bounds arg. With (1024, 4) the compiler capped VGPRs
// at 64 and spilled ~760 MB/dispatch to scratch (measured R2: FETCH 1.05 GB,
// WRITE 761 MB, VGPR_Count=64, 662 us). A 1024-thread block already requires
// 4 waves/SIMD co-resident -> hard cap is 128 VGPR; let the compiler use it.
__launch_bounds__(BLOCK)
__global__ void kdtree_router_kernel(const float* __restrict__ x,
                                     const float* __restrict__ pca_mean,
                                     const float* __restrict__ pca_comp,
                                     const float* __restrict__ centroids,
                                     float* __restrict__ out) {
    // LDS: W staged as [p][h4] f4 (96 KB) + centroids transposed + reduce scratch
    __shared__ f4    sW4[P_DIM * H4];
    __shared__ float sC[P_DIM * E_NUM];
    __shared__ float sRed[WAVES * P_DIM];

    const int tid  = threadIdx.x;
    const int wave = tid >> 6;
    const int lane = tid & 63;

    const f4* Wg4   = (const f4*)pca_comp;
    const f4* mean4 = (const f4*)pca_mean;
    const f4* x4    = (const f4*)x;

    const int n0 = blockIdx.x * TOK_PER_BLOCK + wave * TW;

    // ---- issue x prefetch for iterations 0 and 1 BEFORE staging W ----
    // x is the 268MB stream; get its HBM reads in flight while we stage the
    // 96KB of W + barrier. Nontemporal: streamed once, no reuse, > L3 size.
    f4 xc[TW], xn[TW];
    #pragma unroll
    for (int t = 0; t < TW; ++t)
        xc[t] = __builtin_nontemporal_load(x4 + (n0 + t) * H4 + lane);
    #pragma unroll
    for (int t = 0; t < TW; ++t)
        xn[t] = __builtin_nontemporal_load(x4 + (n0 + t) * H4 + 64 + lane);

    // stage centroids transposed: sC[p][e] = centroids[e*6+p]
    if (tid < E_NUM * P_DIM) {
        int e = tid / P_DIM, p = tid - e * P_DIM;
        sC[p * E_NUM + e] = centroids[tid];
    }

    // stage W into LDS (1024 threads -> exactly one f4 per thread per p);
    // simultaneously compute mean_proj[p] = mean . W[p]
    const f4 m4 = mean4[tid];
    #pragma unroll
    for (int p = 0; p < P_DIM; ++p) {
        f4 w = Wg4[p * H4 + tid];
        sW4[p * H4 + tid] = w;
        float sp = w.x * m4.x + w.y * m4.y + w.z * m4.z + w.w * m4.w;
        #pragma unroll
        for (int off = 32; off > 0; off >>= 1) sp += __shfl_xor(sp, off, 64);
        if (lane == 0) sRed[wave * P_DIM + p] = sp;
    }
    __syncthreads();

    float mp[P_DIM];
    #pragma unroll
    for (int p = 0; p < P_DIM; ++p) {
        float s = 0.f;
        #pragma unroll
        for (int w = 0; w < WAVES; ++w) s += sRed[w * P_DIM + p];
        mp[p] = s;
    }

    float* out_idx = out;                       // [N,8] indices (as float)
    float* out_tp  = out + N_TOK * K_TOP;       // [N,8] renormalized top-k probs
    float* out_pr  = out + 2 * N_TOK * K_TOP;   // [N,64] full softmax

    float acc[TW][P_DIM];
    #pragma unroll
    for (int t = 0; t < TW; ++t)
        #pragma unroll
        for (int p = 0; p < P_DIM; ++p) acc[t][p] = 0.f;

    // main loop, depth-1 pipeline: compute iteration `it` on xc while the
    // loads for it+1 (issued last iteration into xn) are in flight.
    // 16 waves x 4 KB outstanding ~= 53 KB/CU time-averaged >> the ~9 KB
    // Little's-law requirement at 24.6 GB/s/CU -> BW-bound once spill-free.
    for (int it = 0; it < NIT; ++it) {
        const int h4 = it * 64 + lane;
        f4 w[P_DIM];
        #pragma unroll
        for (int p = 0; p < P_DIM; ++p) w[p] = sW4[p * H4 + h4];

        f4 xf[TW];
        const bool more = (it + 2 < NIT);
        if (more) {
            const int h4f = (it + 2) * 64 + lane;
            #pragma unroll
            for (int t = 0; t < TW; ++t)
                xf[t] = __builtin_nontemporal_load(x4 + (n0 + t) * H4 + h4f);
        }

        #pragma unroll
        for (int t = 0; t < TW; ++t) {
            #pragma unroll
            for (int p = 0; p < P_DIM; ++p) {
                acc[t][p] += xc[t].x * w[p].x + xc[t].y * w[p].y
                           + xc[t].z * w[p].z + xc[t].w * w[p].w;
            }
        }

        #pragma unroll
        for (int t = 0; t < TW; ++t) xc[t] = xn[t];
        if (more) {
            #pragma unroll
            for (int t = 0; t < TW; ++t) xn[t] = xf[t];
        }
    }

    // per-token epilogue: reduce proj, distances, softmax, top-8
    #pragma unroll
    for (int t = 0; t < TW; ++t) {
        const int n = n0 + t;
        float pr[P_DIM];
        #pragma unroll
        for (int p = 0; p < P_DIM; ++p) {
            float v = acc[t][p];
            #pragma unroll
            for (int off = 32; off > 0; off >>= 1) v += __shfl_xor(v, off, 64);
            pr[p] = v - mp[p];
        }

        // lane e computes distance to centroid e (direct form, >= 0)
        float d2 = 0.f;
        #pragma unroll
        for (int p = 0; p < P_DIM; ++p) {
            float diff = pr[p] - sC[p * E_NUM + lane];
            d2 += diff * diff;
        }
        float dist = sqrtf(d2);

        // softmax(-dist) across 64 lanes
        float mn = dist;
        #pragma unroll
        for (int off = 32; off > 0; off >>= 1) mn = fminf(mn, __shfl_xor(mn, off, 64));
        float ev  = __expf(mn - dist);
        float sum = ev;
        #pragma unroll
        for (int off = 32; off > 0; off >>= 1) sum += __shfl_xor(sum, off, 64);
        float prob = ev / sum;
        out_pr[n * E_NUM + lane] = prob;

        // top-8 via repeated butterfly argmax (ties -> lower index, matches lax.top_k)
        float v = prob; int idx = lane;
        float tsum = 0.f, myv = 0.f; int myi = 0;
        #pragma unroll
        for (int r = 0; r < K_TOP; ++r) {
            float bv = v; int bi = idx;
            #pragma unroll
            for (int off = 32; off > 0; off >>= 1) {
                float ov = __shfl_xor(bv, off, 64);
                int   oi = __shfl_xor(bi, off, 64);
                if (ov > bv || (ov == bv && oi < bi)) { bv = ov; bi = oi; }
            }
            tsum += bv;
            if (lane == r) { myv = bv; myi = bi; }
            if (idx == bi) v = -1.f;   // remove winner (probs are > 0)
        }
        if (lane < K_TOP) {
            out_idx[n * K_TOP + lane] = (float)myi;
            out_tp [n * K_TOP + lane] = myv / tsum;
        }
    }
}

extern "C" void kernel_launch(void* const* d_in, const int* in_sizes, int n_in,
                              void* d_out, int out_size, void* d_ws, size_t ws_size,
                              hipStream_t stream) {
    const float* x         = (const float*)d_in[0];
    const float* pca_mean  = (const float*)d_in[1];
    const float* pca_comp  = (const float*)d_in[2];
    const float* centroids = (const float*)d_in[3];
    // d_in[4] = top_k (known constant 8)
    float* out = (float*)d_out;

    kdtree_router_kernel<<<GRID, BLOCK, 0, stream>>>(x, pca_mean, pca_comp, centroids, out);
}

// Round 4
// 906.697 us; speedup vs baseline: 1.0162x; 1.0122x over previous
//
#include <hip/hip_runtime.h>

#define N_TOK 16384
#define H_DIM 4096
#define H4    1024      // H/4 (f4 count per row)
#define P_DIM 6
#define E_NUM 64
#define K_TOP 8
#define BLOCK 1024      // 16 waves
#define WAVES 16
#define GRID  256       // 1 block per CU
#define TOK_PER_BLOCK 64   // N_TOK / GRID
#define TW 4               // tokens per wave, processed SEQUENTIALLY
#define NIT 16             // f4-chunks per token per lane (H4/64)
#define NSTEP (TW * NIT)   // 64: wave's flat stream length

// native clang vector: __builtin_nontemporal_load requires this, not HIP float4
typedef float f4 __attribute__((ext_vector_type(4)));

// R2/R3 lesson: the backend budgets 64 VGPRs for this kernel no matter what
// launch_bounds says (memory-bound heuristic -> 8 waves/SIMD target), and
// spilled the old 4-parallel-token pipeline (~100 regs) to scratch: 760 MB
// extra HBM each way, 665 us. Fix: the 4 token rows are CONTIGUOUS, so walk
// them as ONE flat stream with a depth-2 chain (12 regs of pipeline state);
// peak live ~60 regs -> fits the 64 budget, zero scratch.
__launch_bounds__(BLOCK)
__global__ void kdtree_router_kernel(const float* __restrict__ x,
                                     const float* __restrict__ pca_mean,
                                     const float* __restrict__ pca_comp,
                                     const float* __restrict__ centroids,
                                     float* __restrict__ out) {
    __shared__ f4    sW4[P_DIM * H4];     // 96 KB: W[p][h4], served at LDS BW
    __shared__ float sC[P_DIM * E_NUM];   // centroids transposed
    __shared__ float sRed[WAVES * P_DIM]; // mean-proj block reduction

    const int tid  = threadIdx.x;
    const int wave = tid >> 6;
    const int lane = tid & 63;

    const f4* Wg4   = (const f4*)pca_comp;
    const f4* mean4 = (const f4*)pca_mean;
    const f4* x4    = (const f4*)x;

    const int n0 = blockIdx.x * TOK_PER_BLOCK + wave * TW;
    // wave's flat x stream: 64 contiguous 1KB chunks (4 token rows)
    const f4* xw = x4 + (size_t)n0 * H4 + lane;

    // issue first two chunk loads BEFORE staging W: HBM reads in flight
    // under the 96KB stage + barrier. nt: 268MB single-use stream > L3.
    f4 xc = __builtin_nontemporal_load(xw);
    f4 xn = __builtin_nontemporal_load(xw + 64);

    // stage centroids transposed: sC[p][e] = centroids[e*6+p]
    if (tid < E_NUM * P_DIM) {
        int e = tid / P_DIM, p = tid - e * P_DIM;
        sC[p * E_NUM + e] = centroids[tid];
    }

    // stage W into LDS (1024 threads -> one f4 per thread per p);
    // simultaneously compute mean_proj[p] = mean . W[p]
    const f4 m4 = mean4[tid];
    #pragma unroll
    for (int p = 0; p < P_DIM; ++p) {
        f4 w = Wg4[p * H4 + tid];
        sW4[p * H4 + tid] = w;
        float sp = w.x * m4.x + w.y * m4.y + w.z * m4.z + w.w * m4.w;
        #pragma unroll
        for (int off = 32; off > 0; off >>= 1) sp += __shfl_xor(sp, off, 64);
        if (lane == 0) sRed[wave * P_DIM + p] = sp;
    }
    __syncthreads();

    float mp[P_DIM];
    #pragma unroll
    for (int p = 0; p < P_DIM; ++p) {
        float s = 0.f;
        #pragma unroll
        for (int w = 0; w < WAVES; ++w) s += sRed[w * P_DIM + p];
        mp[p] = s;
    }

    float* out_idx = out;                       // [N,8] indices (as float)
    float* out_tp  = out + N_TOK * K_TOP;       // [N,8] renormalized top-k probs
    float* out_pr  = out + 2 * N_TOK * K_TOP;   // [N,64] full softmax

    float acc[P_DIM];
    #pragma unroll
    for (int p = 0; p < P_DIM; ++p) acc[p] = 0.f;

    // ---- main: tokens sequential; flat stream step s = t*16 + it ----
    for (int t = 0; t < TW; ++t) {
        #pragma unroll
        for (int it = 0; it < NIT; ++it) {
            const int s = t * NIT + it;
            // prefetch step s+2 (depth-2 chain)
            f4 xf;
            const bool more = (s + 2 < NSTEP);
            if (more) xf = __builtin_nontemporal_load(xw + (s + 2) * 64);

            f4 w[P_DIM];
            #pragma unroll
            for (int p = 0; p < P_DIM; ++p) w[p] = sW4[p * H4 + it * 64 + lane];

            #pragma unroll
            for (int p = 0; p < P_DIM; ++p) {
                acc[p] += xc.x * w[p].x + xc.y * w[p].y
                        + xc.z * w[p].z + xc.w * w[p].w;
            }
            xc = xn;
            if (more) xn = xf;
        }

        // ---- per-token epilogue (token n = n0 + t) ----
        const int n = n0 + t;
        float pr[P_DIM];
        #pragma unroll
        for (int p = 0; p < P_DIM; ++p) {
            float v = acc[p];
            #pragma unroll
            for (int off = 32; off > 0; off >>= 1) v += __shfl_xor(v, off, 64);
            pr[p] = v - mp[p];
            acc[p] = 0.f;   // reset for next token
        }

        // lane e computes distance to centroid e (direct form, >= 0)
        float d2 = 0.f;
        #pragma unroll
        for (int p = 0; p < P_DIM; ++p) {
            float diff = pr[p] - sC[p * E_NUM + lane];
            d2 += diff * diff;
        }
        float dist = sqrtf(d2);

        // softmax(-dist) across 64 lanes
        float mn = dist;
        #pragma unroll
        for (int off = 32; off > 0; off >>= 1) mn = fminf(mn, __shfl_xor(mn, off, 64));
        float ev  = __expf(mn - dist);
        float sum = ev;
        #pragma unroll
        for (int off = 32; off > 0; off >>= 1) sum += __shfl_xor(sum, off, 64);
        float prob = ev / sum;
        out_pr[n * E_NUM + lane] = prob;

        // top-8 via repeated butterfly argmax (ties -> lower index, matches lax.top_k)
        float v = prob; int idx = lane;
        float tsum = 0.f, myv = 0.f; int myi = 0;
        #pragma unroll
        for (int r = 0; r < K_TOP; ++r) {
            float bv = v; int bi = idx;
            #pragma unroll
            for (int off = 32; off > 0; off >>= 1) {
                float ov = __shfl_xor(bv, off, 64);
                int   oi = __shfl_xor(bi, off, 64);
                if (ov > bv || (ov == bv && oi < bi)) { bv = ov; bi = oi; }
            }
            tsum += bv;
            if (lane == r) { myv = bv; myi = bi; }
            if (idx == bi) v = -1.f;   // remove winner (probs are > 0)
        }
        if (lane < K_TOP) {
            out_idx[n * K_TOP + lane] = (float)myi;
            out_tp [n * K_TOP + lane] = myv / tsum;
        }
    }
}

extern "C" void kernel_launch(void* const* d_in, const int* in_sizes, int n_in,
                              void* d_out, int out_size, void* d_ws, size_t ws_size,
                              hipStream_t stream) {
    const float* x         = (const float*)d_in[0];
    const float* pca_mean  = (const float*)d_in[1];
    const float* pca_comp  = (const float*)d_in[2];
    const float* centroids = (const float*)d_in[3];
    // d_in[4] = top_k (known constant 8)
    float* out = (float*)d_out;

    kdtree_router_kernel<<<GRID, BLOCK, 0, stream>>>(x, pca_mean, pca_comp, centroids, out);
}

// Round 5
// 415.091 us; speedup vs baseline: 2.2197x; 2.1843x over previous
//
#include <hip/hip_runtime.h>

#define N_TOK 16384
#define H_DIM 4096
#define H4    1024      // H/4 (float4 count per row)
#define P_DIM 6
#define E_NUM 64
#define K_TOP 8
#define BLOCK 1024      // 16 waves
#define WAVES 16
#define GRID  256       // 1 block per CU
#define TOK_PER_BLOCK 64   // N_TOK / GRID
#define TW 4               // tokens per wave
#define NIT (H4 / 64)      // 16 main-loop iterations

// R2-R4 lesson: with this kernel the backend's occupancy heuristic budgets
// 64 VGPRs (targets 8 waves/SIMD, ignoring that 100KB LDS caps us at 1
// block/CU = 4 waves/SIMD) and spills the pipeline loop-carried: 0.5-0.9 GB
// of scratch traffic each way, 650-665 us vs baseline ~156 us.
// amdgpu_waves_per_eu(4,4) pins the target to the LDS-implied occupancy ->
// 128-reg budget. Also: NO __builtin_nontemporal_load (suspected TCC
// over-fetch: FETCH rose to 1.19 GB in R4 beyond symmetric spill traffic).
__global__
__attribute__((amdgpu_flat_work_group_size(BLOCK, BLOCK), amdgpu_waves_per_eu(4, 4)))
void kdtree_router_kernel(const float* __restrict__ x,
                          const float* __restrict__ pca_mean,
                          const float* __restrict__ pca_comp,
                          const float* __restrict__ centroids,
                          float* __restrict__ out) {
    // LDS: W staged as [p][h4] float4 (96 KB) + centroids transposed + reduce scratch
    __shared__ float4 sW4[P_DIM * H4];
    __shared__ float  sC[P_DIM * E_NUM];
    __shared__ float  sRed[WAVES * P_DIM];

    const int tid  = threadIdx.x;
    const int wave = tid >> 6;
    const int lane = tid & 63;

    const float4* Wg4   = (const float4*)pca_comp;
    const float4* mean4 = (const float4*)pca_mean;
    const float4* x4    = (const float4*)x;

    const int n0 = blockIdx.x * TOK_PER_BLOCK + wave * TW;

    // early prefetch: first x chunk per token stream issued BEFORE the 96KB
    // W staging + barrier, so the HBM stream starts immediately. Plain
    // cached loads (16 regs live across the barrier -- safe at 128 budget).
    float4 xc[TW];
    #pragma unroll
    for (int t = 0; t < TW; ++t) xc[t] = x4[(n0 + t) * H4 + lane];

    // stage centroids transposed: sC[p][e] = centroids[e*6+p]
    if (tid < E_NUM * P_DIM) {
        int e = tid / P_DIM, p = tid - e * P_DIM;
        sC[p * E_NUM + e] = centroids[tid];
    }

    // stage W into LDS (1024 threads -> exactly one float4 per thread per p);
    // simultaneously compute mean_proj[p] = mean . W[p]
    const float4 m4 = mean4[tid];
    #pragma unroll
    for (int p = 0; p < P_DIM; ++p) {
        float4 w = Wg4[p * H4 + tid];
        sW4[p * H4 + tid] = w;
        float sp = w.x * m4.x + w.y * m4.y + w.z * m4.z + w.w * m4.w;
        #pragma unroll
        for (int off = 32; off > 0; off >>= 1) sp += __shfl_xor(sp, off, 64);
        if (lane == 0) sRed[wave * P_DIM + p] = sp;
    }
    __syncthreads();

    float mp[P_DIM];
    #pragma unroll
    for (int p = 0; p < P_DIM; ++p) {
        float s = 0.f;
        #pragma unroll
        for (int w = 0; w < WAVES; ++w) s += sRed[w * P_DIM + p];
        mp[p] = s;
    }

    float* out_idx = out;                       // [N,8] indices (as float)
    float* out_tp  = out + N_TOK * K_TOP;       // [N,8] renormalized top-k probs
    float* out_pr  = out + 2 * N_TOK * K_TOP;   // [N,64] full softmax

    float acc[TW][P_DIM];
    #pragma unroll
    for (int t = 0; t < TW; ++t)
        #pragma unroll
        for (int p = 0; p < P_DIM; ++p) acc[t][p] = 0.f;

    // main loop, depth-1 pipeline (proven baseline structure): compute it on
    // xc while the loads for it+1 stream into xn.
    for (int it = 0; it < NIT; ++it) {
        float4 xn[TW];
        if (it < NIT - 1) {
            int h4n = (it + 1) * 64 + lane;
            #pragma unroll
            for (int t = 0; t < TW; ++t) xn[t] = x4[(n0 + t) * H4 + h4n];
        }
        const int h4 = it * 64 + lane;
        float4 w[P_DIM];
        #pragma unroll
        for (int p = 0; p < P_DIM; ++p) w[p] = sW4[p * H4 + h4];

        #pragma unroll
        for (int t = 0; t < TW; ++t) {
            #pragma unroll
            for (int p = 0; p < P_DIM; ++p) {
                acc[t][p] += xc[t].x * w[p].x + xc[t].y * w[p].y
                           + xc[t].z * w[p].z + xc[t].w * w[p].w;
            }
        }
        if (it < NIT - 1) {
            #pragma unroll
            for (int t = 0; t < TW; ++t) xc[t] = xn[t];
        }
    }

    // per-token epilogue: reduce proj, distances, softmax, top-8
    #pragma unroll
    for (int t = 0; t < TW; ++t) {
        const int n = n0 + t;
        float pr[P_DIM];
        #pragma unroll
        for (int p = 0; p < P_DIM; ++p) {
            float v = acc[t][p];
            #pragma unroll
            for (int off = 32; off > 0; off >>= 1) v += __shfl_xor(v, off, 64);
            pr[p] = v - mp[p];
        }

        // lane e computes distance to centroid e (direct form, >= 0)
        float d2 = 0.f;
        #pragma unroll
        for (int p = 0; p < P_DIM; ++p) {
            float diff = pr[p] - sC[p * E_NUM + lane];
            d2 += diff * diff;
        }
        float dist = sqrtf(d2);

        // softmax(-dist) across 64 lanes
        float mn = dist;
        #pragma unroll
        for (int off = 32; off > 0; off >>= 1) mn = fminf(mn, __shfl_xor(mn, off, 64));
        float ev  = __expf(mn - dist);
        float sum = ev;
        #pragma unroll
        for (int off = 32; off > 0; off >>= 1) sum += __shfl_xor(sum, off, 64);
        float prob = ev / sum;
        out_pr[n * E_NUM + lane] = prob;

        // top-8 via repeated butterfly argmax (ties -> lower index, matches lax.top_k)
        float v = prob; int idx = lane;
        float tsum = 0.f, myv = 0.f; int myi = 0;
        #pragma unroll
        for (int r = 0; r < K_TOP; ++r) {
            float bv = v; int bi = idx;
            #pragma unroll
            for (int off = 32; off > 0; off >>= 1) {
                float ov = __shfl_xor(bv, off, 64);
                int   oi = __shfl_xor(bi, off, 64);
                if (ov > bv || (ov == bv && oi < bi)) { bv = ov; bi = oi; }
            }
            tsum += bv;
            if (lane == r) { myv = bv; myi = bi; }
            if (idx == bi) v = -1.f;   // remove winner (probs are > 0)
        }
        if (lane < K_TOP) {
            out_idx[n * K_TOP + lane] = (float)myi;
            out_tp [n * K_TOP + lane] = myv / tsum;
        }
    }
}

extern "C" void kernel_launch(void* const* d_in, const int* in_sizes, int n_in,
                              void* d_out, int out_size, void* d_ws, size_t ws_size,
                              hipStream_t stream) {
    const float* x         = (const float*)d_in[0];
    const float* pca_mean  = (const float*)d_in[1];
    const float* pca_comp  = (const float*)d_in[2];
    const float* centroids = (const float*)d_in[3];
    // d_in[4] = top_k (known constant 8)
    float* out = (float*)d_out;

    kdtree_router_kernel<<<GRID, BLOCK, 0, stream>>>(x, pca_mean, pca_comp, centroids, out);
}

// Round 6
// 376.225 us; speedup vs baseline: 2.4490x; 1.1033x over previous
//
#include <hip/hip_runtime.h>

#define N_TOK 16384
#define H_DIM 4096
#define H4    1024      // H/4 (float4 count per row)
#define P_DIM 6
#define E_NUM 64
#define K_TOP 8
#define BLOCK 1024      // 16 waves
#define WAVES 16
#define GRID  256       // 1 block per CU
#define TOK_PER_BLOCK 64   // N_TOK / GRID
#define NCH   16           // 1KB chunks per 16KB row
#define NSTEP 64           // 4 tokens x 16 chunks: wave's flat step count

// R2-R5 history:
//  - (1024,4) launch_bounds or default -> backend budgets 64 VGPR and spills
//    any >64-reg pipeline loop-carried (0.5-0.9 GB scratch traffic, 650+ us).
//  - amdgpu_waves_per_eu(4,4) (R5) -> 128-reg budget, no spill, 156 us kernel.
//  - 156 us = 1.9 TB/s effective on the 268 MB x stream vs fills' 6.7 TB/s.
//    Theory: baseline reads 4 rows in parallel at 16 KB stride -> per-CU
//    instantaneous footprint = 64 scattered 1 KB chunks over 1 MB ->
//    HBM row-buffer thrash. This version streams each row SEQUENTIALLY
//    (wave w owns tokens n0+k*16+w; per-CU footprint = 16 consecutive rows,
//    one contiguous 256 KB window). Numerics bit-identical to R5.
__global__
__attribute__((amdgpu_flat_work_group_size(BLOCK, BLOCK), amdgpu_waves_per_eu(4, 4)))
void kdtree_router_kernel(const float* __restrict__ x,
                          const float* __restrict__ pca_mean,
                          const float* __restrict__ pca_comp,
                          const float* __restrict__ centroids,
                          float* __restrict__ out) {
    __shared__ float4 sW4[P_DIM * H4];     // 96 KB: W[p][h4]
    __shared__ float  sC[P_DIM * E_NUM];   // centroids transposed
    __shared__ float  sRed[WAVES * P_DIM]; // mean-proj block reduction

    const int tid  = threadIdx.x;
    const int wave = tid >> 6;
    const int lane = tid & 63;

    const float4* Wg4   = (const float4*)pca_comp;
    const float4* mean4 = (const float4*)pca_mean;
    const float4* x4    = (const float4*)x;

    // wave's pass-k token: blk*64 + k*16 + wave; flat step s = k*16 + c
    // f4 index: idx(s) = base + (s>>4)*(WAVES*H4) + (s&15)*64
    const int base = (blockIdx.x * TOK_PER_BLOCK + wave) * H4 + lane;

    // early prefetch: first two chunks of the wave's first token issued
    // BEFORE the 96KB W staging + barrier (8 regs live across the barrier).
    float4 xc = x4[base];
    float4 xn = x4[base + 64];

    // stage centroids transposed: sC[p][e] = centroids[e*6+p]
    if (tid < E_NUM * P_DIM) {
        int e = tid / P_DIM, p = tid - e * P_DIM;
        sC[p * E_NUM + e] = centroids[tid];
    }

    // stage W into LDS (one float4 per thread per p); fold in
    // mean_proj[p] = mean . W[p]
    const float4 m4 = mean4[tid];
    #pragma unroll
    for (int p = 0; p < P_DIM; ++p) {
        float4 w = Wg4[p * H4 + tid];
        sW4[p * H4 + tid] = w;
        float sp = w.x * m4.x + w.y * m4.y + w.z * m4.z + w.w * m4.w;
        #pragma unroll
        for (int off = 32; off > 0; off >>= 1) sp += __shfl_xor(sp, off, 64);
        if (lane == 0) sRed[wave * P_DIM + p] = sp;
    }
    __syncthreads();

    float mp[P_DIM];
    #pragma unroll
    for (int p = 0; p < P_DIM; ++p) {
        float s = 0.f;
        #pragma unroll
        for (int w = 0; w < WAVES; ++w) s += sRed[w * P_DIM + p];
        mp[p] = s;
    }

    float* out_idx = out;                       // [N,8] indices (as float)
    float* out_tp  = out + N_TOK * K_TOP;       // [N,8] renormalized top-k probs
    float* out_pr  = out + 2 * N_TOK * K_TOP;   // [N,64] full softmax

    float acc[P_DIM];
    #pragma unroll
    for (int p = 0; p < P_DIM; ++p) acc[p] = 0.f;

    // Flat 64-step stream, ROLLED (unroll 1: prevents the scheduler from
    // cluster-hoisting prefetch loads -> reg blowup -> spill, the R2/R4
    // failure). Depth-2 chain xc/xn/xf; prefetch crosses token boundaries
    // naturally, so each epilogue hides the next token's load latency.
    #pragma unroll 1
    for (int s = 0; s < NSTEP; ++s) {
        const int sp2 = (s + 2 < NSTEP) ? (s + 2) : (NSTEP - 1); // tail re-read, L1-hot
        const float4 xf = x4[base + ((sp2 >> 4) << 14) + ((sp2 & 15) << 6)];

        const int c = s & 15;
        float4 w[P_DIM];
        #pragma unroll
        for (int p = 0; p < P_DIM; ++p) w[p] = sW4[p * H4 + c * 64 + lane];

        #pragma unroll
        for (int p = 0; p < P_DIM; ++p) {
            acc[p] += xc.x * w[p].x + xc.y * w[p].y
                    + xc.z * w[p].z + xc.w * w[p].w;
        }
        xc = xn;
        xn = xf;

        if (c == NCH - 1) {
            // token finished; epilogue (wave-uniform branch)
            const int n = blockIdx.x * TOK_PER_BLOCK + (s >> 4) * WAVES + wave;

            float pr[P_DIM];
            #pragma unroll
            for (int p = 0; p < P_DIM; ++p) {
                float v = acc[p];
                #pragma unroll
                for (int off = 32; off > 0; off >>= 1) v += __shfl_xor(v, off, 64);
                pr[p] = v - mp[p];
                acc[p] = 0.f;   // reset for next token
            }

            // lane e computes distance to centroid e (direct form, >= 0)
            float d2 = 0.f;
            #pragma unroll
            for (int p = 0; p < P_DIM; ++p) {
                float diff = pr[p] - sC[p * E_NUM + lane];
                d2 += diff * diff;
            }
            float dist = sqrtf(d2);

            // softmax(-dist) across 64 lanes
            float mn = dist;
            #pragma unroll
            for (int off = 32; off > 0; off >>= 1) mn = fminf(mn, __shfl_xor(mn, off, 64));
            float ev  = __expf(mn - dist);
            float sum = ev;
            #pragma unroll
            for (int off = 32; off > 0; off >>= 1) sum += __shfl_xor(sum, off, 64);
            float prob = ev / sum;
            out_pr[n * E_NUM + lane] = prob;

            // top-8 via repeated butterfly argmax (ties -> lower index)
            float v = prob; int idx = lane;
            float tsum = 0.f, myv = 0.f; int myi = 0;
            #pragma unroll
            for (int r = 0; r < K_TOP; ++r) {
                float bv = v; int bi = idx;
                #pragma unroll
                for (int off = 32; off > 0; off >>= 1) {
                    float ov = __shfl_xor(bv, off, 64);
                    int   oi = __shfl_xor(bi, off, 64);
                    if (ov > bv || (ov == bv && oi < bi)) { bv = ov; bi = oi; }
                }
                tsum += bv;
                if (lane == r) { myv = bv; myi = bi; }
                if (idx == bi) v = -1.f;   // remove winner (probs are > 0)
            }
            if (lane < K_TOP) {
                out_idx[n * K_TOP + lane] = (float)myi;
                out_tp [n * K_TOP + lane] = myv / tsum;
            }
        }
    }
}

extern "C" void kernel_launch(void* const* d_in, const int* in_sizes, int n_in,
                              void* d_out, int out_size, void* d_ws, size_t ws_size,
                              hipStream_t stream) {
    const float* x         = (const float*)d_in[0];
    const float* pca_mean  = (const float*)d_in[1];
    const float* pca_comp  = (const float*)d_in[2];
    const float* centroids = (const float*)d_in[3];
    // d_in[4] = top_k (known constant 8)
    float* out = (float*)d_out;

    kdtree_router_kernel<<<GRID, BLOCK, 0, stream>>>(x, pca_mean, pca_comp, centroids, out);
}